// Round 3
// baseline (30.118 us; speedup 1.0000x reference)
//
#include <hip/hip_runtime.h>
#include <hip/hip_bf16.h>

#define NB 64
#define LQ 32
#define LD 256
#define DD 128
#define NWAY 8
#define KQ 64            // doc rows per block (k-quarter)
#define LDSROW 136       // 128 + 8 bf16 pad -> 272B row stride, 16B aligned

typedef __attribute__((ext_vector_type(8))) short short8;
typedef __attribute__((ext_vector_type(4))) float f32x4;

static __device__ __forceinline__ unsigned short f2bf(float f) {
    unsigned int u = __float_as_uint(f);
    u += 0x7fffu + ((u >> 16) & 1u);   // round-to-nearest-even
    return (unsigned short)(u >> 16);
}
static __device__ __forceinline__ unsigned int pk2(float a, float b) {
    return (unsigned int)f2bf(a) | ((unsigned int)f2bf(b) << 16);
}

// grid = 2048: block bid handles (bn = bid>>2, k-quarter hq = bid&3).
// 256 threads = 4 waves: wave = (kq<<1)|qh; kq picks 32 of the 64 k cols.
// Doc rows stored UNNORMALIZED bf16; 1/||d|| applied post-MFMA per column.
__global__ __launch_bounds__(256, 4) void colbert_part_kernel(
    const float* __restrict__ qreps,   // [B][LQ][DD]
    const float* __restrict__ dreps,   // [B][NWAY][LD][DD]
    const int*   __restrict__ masks,   // [B][NWAY][LD]
    float*       __restrict__ qpart)   // [2048][LQ] per-q partial max
{
    const int bid  = blockIdx.x;
    const int bn   = bid >> 2;
    const int hq   = bid & 3;
    const int b    = bn >> 3;
    const int tid  = threadIdx.x;
    const int lane = tid & 63;
    const int w    = tid >> 6;

    __shared__ __align__(16) unsigned short qs[LQ * LDSROW];   // normalized q, bf16
    __shared__ __align__(16) unsigned short ds_[KQ * LDSROW];  // raw doc rows, bf16
    __shared__ float rnds[KQ];
    __shared__ int   mks[KQ];
    __shared__ float qmaxs[2][LQ];

    // ---- issue ALL global loads up front (no gating dependencies) ----
    const int drow = tid >> 2, dseg = tid & 3;          // 4 threads/row, 32 floats
    const float* dsrc = dreps + ((size_t)bn * LD + hq * KQ + drow) * DD + dseg * 32;
    float4 df[8];
    #pragma unroll
    for (int i = 0; i < 8; ++i) df[i] = reinterpret_cast<const float4*>(dsrc)[i];

    const int qrow = tid >> 3, qseg = tid & 7;          // 8 threads/row, 16 floats
    const float* qsrc = qreps + ((size_t)b * LQ + qrow) * DD + qseg * 16;
    float4 qf[4];
    #pragma unroll
    for (int i = 0; i < 4; ++i) qf[i] = reinterpret_cast<const float4*>(qsrc)[i];

    if (tid < KQ) mks[tid] = masks[(size_t)bn * LD + hq * KQ + tid];

    // ---- doc rows: ssq + pack raw bf16 -> LDS; 1/norm -> rnds ----
    {
        float ss = 0.f;
        unsigned int dp[16];
        #pragma unroll
        for (int i = 0; i < 8; ++i) {
            ss += df[i].x*df[i].x + df[i].y*df[i].y + df[i].z*df[i].z + df[i].w*df[i].w;
            dp[2*i]   = pk2(df[i].x, df[i].y);
            dp[2*i+1] = pk2(df[i].z, df[i].w);
        }
        unsigned short* dst = &ds_[drow * LDSROW + dseg * 32];
        #pragma unroll
        for (int i = 0; i < 4; ++i)
            reinterpret_cast<uint4*>(dst)[i] = *reinterpret_cast<const uint4*>(&dp[4*i]);
        ss += __shfl_xor(ss, 1); ss += __shfl_xor(ss, 2);
        if (dseg == 0) rnds[drow] = rsqrtf(fmaxf(ss, 1e-24f));
    }

    // ---- q rows: normalize, pack -> LDS ----
    {
        float ss = 0.f;
        #pragma unroll
        for (int i = 0; i < 4; ++i)
            ss += qf[i].x*qf[i].x + qf[i].y*qf[i].y + qf[i].z*qf[i].z + qf[i].w*qf[i].w;
        ss += __shfl_xor(ss, 1); ss += __shfl_xor(ss, 2); ss += __shfl_xor(ss, 4);
        const float rn = rsqrtf(fmaxf(ss, 1e-24f));
        unsigned int qp[8];
        #pragma unroll
        for (int i = 0; i < 4; ++i) {
            qp[2*i]   = pk2(qf[i].x * rn, qf[i].y * rn);
            qp[2*i+1] = pk2(qf[i].z * rn, qf[i].w * rn);
        }
        unsigned short* dst = &qs[qrow * LDSROW + qseg * 16];
        reinterpret_cast<uint4*>(dst)[0] = *reinterpret_cast<const uint4*>(&qp[0]);
        reinterpret_cast<uint4*>(dst)[1] = *reinterpret_cast<const uint4*>(&qp[4]);
    }
    __syncthreads();

    // ---- MFMA: wave covers 16q x 32k (two 16x16 frags) ----
    const int frow  = lane & 15;
    const int fpack = lane >> 4;
    const int qh    = w & 1;
    const int kq    = w >> 1;
    const unsigned short* aptr = &qs[(qh * 16 + frow) * LDSROW + fpack * 8];

    float rmax[2][4];
    #pragma unroll
    for (int fc = 0; fc < 2; ++fc)
        #pragma unroll
        for (int r = 0; r < 4; ++r) rmax[fc][r] = -1e30f;

    #pragma unroll
    for (int fc = 0; fc < 2; ++fc) {
        const int bcol = kq * 32 + fc * 16 + frow;     // doc row index in tile
        const unsigned short* bptr = &ds_[bcol * LDSROW + fpack * 8];
        f32x4 acc = {0.f, 0.f, 0.f, 0.f};
        #pragma unroll
        for (int kc = 0; kc < 4; ++kc) {
            short8 a  = *reinterpret_cast<const short8*>(aptr + kc * 32);
            short8 bb = *reinterpret_cast<const short8*>(bptr + kc * 32);
            acc = __builtin_amdgcn_mfma_f32_16x16x32_bf16(a, bb, acc, 0, 0, 0);
        }
        if (mks[bcol]) {
            const float rnd = rnds[bcol];
            #pragma unroll
            for (int r = 0; r < 4; ++r) rmax[fc][r] = fmaxf(rmax[fc][r], acc[r] * rnd);
        }
    }

    // ---- reduce over 16 k-lanes, combine frags ----
    #pragma unroll
    for (int r = 0; r < 4; ++r) {
        float m0 = rmax[0][r], m1 = rmax[1][r];
        m0 = fmaxf(m0, __shfl_xor(m0, 1)); m1 = fmaxf(m1, __shfl_xor(m1, 1));
        m0 = fmaxf(m0, __shfl_xor(m0, 2)); m1 = fmaxf(m1, __shfl_xor(m1, 2));
        m0 = fmaxf(m0, __shfl_xor(m0, 4)); m1 = fmaxf(m1, __shfl_xor(m1, 4));
        m0 = fmaxf(m0, __shfl_xor(m0, 8)); m1 = fmaxf(m1, __shfl_xor(m1, 8));
        rmax[0][r] = fmaxf(m0, m1);
    }
    if ((lane & 15) == 0) {
        const int qr = qh * 16 + fpack * 4;
        #pragma unroll
        for (int r = 0; r < 4; ++r) qmaxs[kq][qr + r] = rmax[0][r];
    }
    __syncthreads();

    // ---- per-q partial max for this k-quarter -> ws ----
    if (w == 0 && lane < 32)
        qpart[bid * LQ + lane] = fmaxf(qmaxs[0][lane], qmaxs[1][lane]);
}

// One block, 512 threads: thread bn combines 4 quarters, then softmax + KL.
__global__ __launch_bounds__(512) void colbert_loss_kernel(
    const float* __restrict__ qpart,    // [512*4][LQ]
    const float* __restrict__ labels,   // [B][2*NWAY]
    float*       __restrict__ out)
{
    const int bn = threadIdx.x;         // 0..511
    const int b  = bn >> 3;
    const int n  = bn & 7;

    float vmax[LQ];
    const float* src = qpart + (size_t)bn * 4 * LQ;
    #pragma unroll
    for (int i = 0; i < 8; ++i) {
        float4 f = reinterpret_cast<const float4*>(src)[i];
        vmax[4*i] = f.x; vmax[4*i+1] = f.y; vmax[4*i+2] = f.z; vmax[4*i+3] = f.w;
    }
    #pragma unroll
    for (int h = 1; h < 4; ++h) {
        #pragma unroll
        for (int i = 0; i < 8; ++i) {
            float4 f = reinterpret_cast<const float4*>(src + h * LQ)[i];
            vmax[4*i]   = fmaxf(vmax[4*i],   f.x);
            vmax[4*i+1] = fmaxf(vmax[4*i+1], f.y);
            vmax[4*i+2] = fmaxf(vmax[4*i+2], f.z);
            vmax[4*i+3] = fmaxf(vmax[4*i+3], f.w);
        }
    }
    float score = 0.f;
    #pragma unroll
    for (int q = 0; q < LQ; ++q) score += vmax[q];

    // softmax over the 8 n's (consecutive lanes within the wave)
    float m = score;
    m = fmaxf(m, __shfl_xor(m, 1)); m = fmaxf(m, __shfl_xor(m, 2)); m = fmaxf(m, __shfl_xor(m, 4));
    float e = expf(score - m);
    float se = e;
    se += __shfl_xor(se, 1); se += __shfl_xor(se, 2); se += __shfl_xor(se, 4);
    const float lse = m + logf(se);
    const float ls  = score - lse;

    const float tg = labels[b * 2 * NWAY + n];
    const float wv = labels[b * 2 * NWAY + NWAY + n];
    float aterm = expf(tg) * (tg - ls);
    float pterm = ls * wv;

    #pragma unroll
    for (int d = 1; d < 64; d <<= 1) {
        aterm += __shfl_xor(aterm, d);
        pterm += __shfl_xor(pterm, d);
    }
    __shared__ float wa[8], wp[8];
    const int wv_id = threadIdx.x >> 6;
    if ((threadIdx.x & 63) == 0) { wa[wv_id] = aterm; wp[wv_id] = pterm; }
    __syncthreads();
    if (threadIdx.x == 0) {
        float A = 0.f, P = 0.f;
        #pragma unroll
        for (int i = 0; i < 8; ++i) { A += wa[i]; P += wp[i]; }
        out[0] = A / 512.0f - 0.1f * P;
    }
}

extern "C" void kernel_launch(void* const* d_in, const int* in_sizes, int n_in,
                              void* d_out, int out_size, void* d_ws, size_t ws_size,
                              hipStream_t stream) {
    const float* qreps  = (const float*)d_in[0];
    const float* dreps  = (const float*)d_in[1];
    const int*   masks  = (const int*)d_in[2];
    const float* labels = (const float*)d_in[3];
    float* qpart = (float*)d_ws;             // 2048*32 floats = 256 KB
    float* out   = (float*)d_out;

    colbert_part_kernel<<<NB * NWAY * 4, 256, 0, stream>>>(qreps, dreps, masks, qpart);
    colbert_loss_kernel<<<1, 512, 0, stream>>>(qpart, labels, out);
}

// Round 4
// 15.999 us; speedup vs baseline: 1.8825x; 1.8825x over previous
//
#include <hip/hip_runtime.h>
#include <hip/hip_bf16.h>

#define NB 64
#define LQ 32
#define LD 256
#define DD 128
#define NWAY 8
#define KT 64            // doc rows per tile; 4 tiles
#define LDSROW 136       // 128 + 8 bf16 pad -> 272B row stride, 16B aligned

typedef __attribute__((ext_vector_type(8))) short short8;
typedef __attribute__((ext_vector_type(4))) float f32x4;

static __device__ __forceinline__ unsigned short f2bf(float f) {
    unsigned int u = __float_as_uint(f);
    u += 0x7fffu + ((u >> 16) & 1u);   // round-to-nearest-even
    return (unsigned short)(u >> 16);
}
static __device__ __forceinline__ unsigned int pk2(float a, float b) {
    return (unsigned int)f2bf(a) | ((unsigned int)f2bf(b) << 16);
}

// One block per (b,n), 512 threads = 8 waves (wave = kq*2+qh).
// bid mapping b=bid&63, n=bid>>6: blocks sharing b land on the same XCD
// (bids differ by 64 == 0 mod 8) -> Q reads hit that XCD's L2.
// Doc rows: masked rows never loaded; stored UNNORMALIZED bf16, 1/||d||
// applied post-MFMA per column (max commutes with positive scale).
__global__ __launch_bounds__(512, 4) void colbert_scores_kernel(
    const float* __restrict__ qreps,   // [B][LQ][DD]
    const float* __restrict__ dreps,   // [B][NWAY][LD][DD]
    const int*   __restrict__ masks,   // [B][NWAY][LD]
    float*       __restrict__ scores)  // [B*NWAY]
{
    const int bid  = blockIdx.x;
    const int b    = bid & 63;
    const int n    = bid >> 6;
    const int bn   = b * NWAY + n;
    const int tid  = threadIdx.x;
    const int lane = tid & 63;
    const int w    = tid >> 6;

    __shared__ __align__(16) unsigned short qs[LQ * LDSROW];       // normalized q bf16
    __shared__ __align__(16) unsigned short dsb[2][KT * LDSROW];   // raw doc bf16, dbuf
    __shared__ float rnds[2][KT];
    __shared__ int   mks[LD];
    __shared__ float qmaxs[4][LQ];

    // ---- entry: waves 4-7 load masks; waves 0-3 load+normalize Q ----
    if (tid >= 256) {
        const int i = tid - 256;
        mks[i] = masks[(size_t)bn * LD + i];
    } else {
        const int qrow = tid >> 3, qseg = tid & 7;
        const float* src = qreps + ((size_t)b * LQ + qrow) * DD + qseg * 16;
        float4 q0 = reinterpret_cast<const float4*>(src)[0];
        float4 q1 = reinterpret_cast<const float4*>(src)[1];
        float4 q2 = reinterpret_cast<const float4*>(src)[2];
        float4 q3 = reinterpret_cast<const float4*>(src)[3];
        float ss = q0.x*q0.x + q0.y*q0.y + q0.z*q0.z + q0.w*q0.w
                 + q1.x*q1.x + q1.y*q1.y + q1.z*q1.z + q1.w*q1.w
                 + q2.x*q2.x + q2.y*q2.y + q2.z*q2.z + q2.w*q2.w
                 + q3.x*q3.x + q3.y*q3.y + q3.z*q3.z + q3.w*q3.w;
        ss += __shfl_xor(ss, 1); ss += __shfl_xor(ss, 2); ss += __shfl_xor(ss, 4);
        const float rn = rsqrtf(fmaxf(ss, 1e-24f));
        unsigned int qp[8] = {
            pk2(q0.x*rn, q0.y*rn), pk2(q0.z*rn, q0.w*rn),
            pk2(q1.x*rn, q1.y*rn), pk2(q1.z*rn, q1.w*rn),
            pk2(q2.x*rn, q2.y*rn), pk2(q2.z*rn, q2.w*rn),
            pk2(q3.x*rn, q3.y*rn), pk2(q3.z*rn, q3.w*rn) };
        unsigned short* dst = &qs[qrow * LDSROW + qseg * 16];
        reinterpret_cast<uint4*>(dst)[0] = *reinterpret_cast<const uint4*>(&qp[0]);
        reinterpret_cast<uint4*>(dst)[1] = *reinterpret_cast<const uint4*>(&qp[4]);
    }
    __syncthreads();   // mks + qs visible

    const int row = tid >> 3;          // doc row within tile (0..63)
    const int seg = tid & 7;           // 16-float segment
    float va[16], vb[16];

    auto prefetch = [&](float (&v)[16], int t) {
        if (mks[t * KT + row]) {
            const float* src = dreps + ((size_t)bn * LD + t * KT + row) * DD + seg * 16;
            #pragma unroll
            for (int i = 0; i < 4; ++i) {
                float4 f = reinterpret_cast<const float4*>(src)[i];
                v[4*i] = f.x; v[4*i+1] = f.y; v[4*i+2] = f.z; v[4*i+3] = f.w;
            }
        }
    };
    // pack-only staging (no normalize on critical path); rnds deferred scale
    auto stagewrite = [&](float (&v)[16], int t, int bf) {
        if (mks[t * KT + row]) {   // uniform across the row's 8 lanes -> shfl safe
            unsigned int dp[8];
            #pragma unroll
            for (int i = 0; i < 8; ++i) dp[i] = pk2(v[2*i], v[2*i+1]);
            unsigned short* dst = &dsb[bf][row * LDSROW + seg * 16];
            reinterpret_cast<uint4*>(dst)[0] = *reinterpret_cast<const uint4*>(&dp[0]);
            reinterpret_cast<uint4*>(dst)[1] = *reinterpret_cast<const uint4*>(&dp[4]);
            float ss = 0.f;
            #pragma unroll
            for (int i = 0; i < 16; ++i) ss += v[i] * v[i];
            ss += __shfl_xor(ss, 1); ss += __shfl_xor(ss, 2); ss += __shfl_xor(ss, 4);
            if (seg == 0) rnds[bf][row] = rsqrtf(fmaxf(ss, 1e-24f));
        }
    };

    const int frow  = lane & 15;
    const int fpack = lane >> 4;
    const int qh    = w & 1;
    const int kq    = w >> 1;
    const unsigned short* aptr = &qs[(qh * 16 + frow) * LDSROW + fpack * 8];

    float rmax[4] = {-1e30f, -1e30f, -1e30f, -1e30f};

    auto mfma_max = [&](int t, int bf) {
        const int drow = kq * 16 + frow;   // doc row within tile -> output column
        const unsigned short* bptr = &dsb[bf][drow * LDSROW + fpack * 8];
        f32x4 acc = {0.f, 0.f, 0.f, 0.f};
        #pragma unroll
        for (int kc = 0; kc < 4; ++kc) {
            short8 a  = *reinterpret_cast<const short8*>(aptr + kc * 32);
            short8 bb = *reinterpret_cast<const short8*>(bptr + kc * 32);
            acc = __builtin_amdgcn_mfma_f32_16x16x32_bf16(a, bb, acc, 0, 0, 0);
        }
        if (mks[t * KT + drow]) {
            const float rnd = rnds[bf][drow];
            #pragma unroll
            for (int r = 0; r < 4; ++r) rmax[r] = fmaxf(rmax[r], acc[r] * rnd);
        }
    };

    // ---- 4-tile pipeline, 2 LDS buffers, distance-2 register prefetch ----
    prefetch(va, 0);  prefetch(vb, 1);
    stagewrite(va, 0, 0);
    __syncthreads();               // dsb[0] (t0) ready
    prefetch(va, 2);
    mfma_max(0, 0);                // read dsb[0]
    stagewrite(vb, 1, 1);          // write dsb[1]
    __syncthreads();               // dsb[1] (t1) ready, dsb[0] free
    prefetch(vb, 3);
    mfma_max(1, 1);
    stagewrite(va, 2, 0);
    __syncthreads();
    mfma_max(2, 0);
    stagewrite(vb, 3, 1);
    __syncthreads();
    mfma_max(3, 1);

    // ---- reduce max over 16 doc-columns within wave ----
    #pragma unroll
    for (int r = 0; r < 4; ++r) {
        float m = rmax[r];
        m = fmaxf(m, __shfl_xor(m, 1));
        m = fmaxf(m, __shfl_xor(m, 2));
        m = fmaxf(m, __shfl_xor(m, 4));
        m = fmaxf(m, __shfl_xor(m, 8));
        rmax[r] = m;
    }
    if ((lane & 15) == 0) {
        const int qr = qh * 16 + fpack * 4;
        #pragma unroll
        for (int r = 0; r < 4; ++r) qmaxs[kq][qr + r] = rmax[r];
    }
    __syncthreads();

    if (w == 0) {
        float s = 0.f;
        if (lane < 32)
            s = fmaxf(fmaxf(qmaxs[0][lane], qmaxs[1][lane]),
                      fmaxf(qmaxs[2][lane], qmaxs[3][lane]));
        s += __shfl_xor(s, 1);  s += __shfl_xor(s, 2);  s += __shfl_xor(s, 4);
        s += __shfl_xor(s, 8);  s += __shfl_xor(s, 16); s += __shfl_xor(s, 32);
        if (lane == 0) scores[bn] = s;
    }
}

// One wave: thread b handles batch row b.
__global__ __launch_bounds__(64) void colbert_loss_kernel(
    const float* __restrict__ scores,   // [B*NWAY]
    const float* __restrict__ labels,   // [B][2*NWAY]
    float*       __restrict__ out)
{
    const int b = threadIdx.x;
    float sc[NWAY];
    float m = -1e30f;
    #pragma unroll
    for (int j = 0; j < NWAY; ++j) { sc[j] = scores[b * NWAY + j]; m = fmaxf(m, sc[j]); }
    float se = 0.f;
    #pragma unroll
    for (int j = 0; j < NWAY; ++j) se += expf(sc[j] - m);
    const float lse = m + logf(se);

    float lossb = 0.f, posb = 0.f;
    #pragma unroll
    for (int j = 0; j < NWAY; ++j) {
        const float ls = sc[j] - lse;
        const float tg = labels[b * 2 * NWAY + j];
        const float wv = labels[b * 2 * NWAY + NWAY + j];
        lossb += expf(tg) * (tg - ls);
        posb  += ls * wv;
    }
    float a = lossb, p = posb;
    #pragma unroll
    for (int d = 1; d < 64; d <<= 1) { a += __shfl_xor(a, d); p += __shfl_xor(p, d); }
    if (b == 0) out[0] = a / 512.0f - 0.1f * p;
}

extern "C" void kernel_launch(void* const* d_in, const int* in_sizes, int n_in,
                              void* d_out, int out_size, void* d_ws, size_t ws_size,
                              hipStream_t stream) {
    const float* qreps  = (const float*)d_in[0];
    const float* dreps  = (const float*)d_in[1];
    const int*   masks  = (const int*)d_in[2];
    const float* labels = (const float*)d_in[3];
    float* scores = (float*)d_ws;            // 512 floats
    float* out    = (float*)d_out;

    colbert_scores_kernel<<<NB * NWAY, 512, 0, stream>>>(qreps, dreps, masks, scores);
    colbert_loss_kernel<<<1, 64, 0, stream>>>(scores, labels, out);
}